// Round 7
// baseline (179.006 us; speedup 1.0000x reference)
//
#include <hip/hip_runtime.h>
#include <math.h>

// Problem constants
#define B_  8
#define D_  128
#define L_  2048
#define H_  8
#define DH_ 16

#define LOG2E 1.4426950408889634f

typedef __bf16 bf16x8 __attribute__((ext_vector_type(8)));
typedef float  floatx4 __attribute__((ext_vector_type(4)));
typedef float  floatx16 __attribute__((ext_vector_type(16)));

#if __has_builtin(__builtin_amdgcn_exp2f)
#define EXP2(x) __builtin_amdgcn_exp2f(x)
#else
#define EXP2(x) exp2f(x)
#endif

// tau: swap bits 2,3 of a row index (K A-frag row permutation, involution
// within each aligned 16-row group).
__device__ __forceinline__ int tau16(int x) {
  return (x & ~12) | ((x & 4) << 1) | ((x & 8) >> 1);
}

// ---------------------------------------------------------------------------
// Weight pre-convert: fp32 W -> bf16 MFMA frag layout (lane idx = col,
// k = quad*8+j). tiles 0..7 = Q heads (W_q pre-scaled by DH^-0.5 * log2e so
// attn softmax is exp2(s)), 8..15 = K, 16..23 = V.
// ---------------------------------------------------------------------------
__global__ __launch_bounds__(256) void wconv_kernel(
    const float* __restrict__ wmem, const float* __restrict__ wq,
    __bf16* __restrict__ Wb) {
  const int tile = blockIdx.x;
  const int tid = threadIdx.x;
  const int kc = tid >> 6, lane = tid & 63;
  const int quad = lane >> 4, col = lane & 15;
  const float* src;
  float scale = 1.0f;
  if (tile < 8) {
    src = wq + (tile * 16 + col) * D_;
    scale = 0.25f * LOG2E;  // DH^-0.5 and log2e folded into W_q
  } else if (tile < 16) {
    src = wmem + ((tile - 8) * 16 + col) * D_;
  } else {
    src = wmem + (128 + (tile - 16) * 16 + col) * D_;
  }
  const float* p = src + kc * 32 + quad * 8;
  bf16x8 w;
#pragma unroll
  for (int j = 0; j < 8; ++j) w[j] = (__bf16)(p[j] * scale);
  *(bf16x8*)(Wb + ((size_t)((tile * 4 + kc) * 64) + lane) * 8) = w;
}

// ---------------------------------------------------------------------------
// Mask prefix scan: per batch b, sel[b][p] = l of the p-th unmasked key,
// cnt[b] = number of unmasked keys. One block per b.
// ---------------------------------------------------------------------------
__global__ __launch_bounds__(256) void scan_kernel(
    const int* __restrict__ mask, int* __restrict__ sel,
    int* __restrict__ cnt) {
  __shared__ int tsum[256];
  __shared__ int tbase[256];
  const int b = blockIdx.x, tid = threadIdx.x;
  int m[8], s = 0;
  const int* mp = mask + b * L_ + tid * 8;
#pragma unroll
  for (int j = 0; j < 8; ++j) { m[j] = mp[j]; s += m[j]; }
  tsum[tid] = s;
  __syncthreads();
  if (tid == 0) {
    int a = 0;
#pragma unroll 1
    for (int i = 0; i < 256; ++i) { tbase[i] = a; a += tsum[i]; }
    cnt[b] = a;
  }
  __syncthreads();
  int p = tbase[tid];
  int* sb = sel + b * L_;
#pragma unroll
  for (int j = 0; j < 8; ++j) {
    if (m[j]) sb[p++] = tid * 8 + j;
  }
}

// ---------------------------------------------------------------------------
// Projection v3 (round-6, unchanged): MFMA -> LDS staging -> coalesced
// stores. V stored FLAT row-major Vpx[bh][row][l] (row stride L_):
// rows 0-15 = V^T*mask, row 16 = mask. Qs natural; Ks tau-permuted (dense).
// ---------------------------------------------------------------------------
__global__ __launch_bounds__(256) void proj_kernel(
    const float* __restrict__ qin, const int* __restrict__ mask,
    const __bf16* __restrict__ Wb, __bf16* __restrict__ Qs,
    __bf16* __restrict__ Ks, __bf16* __restrict__ Vpx) {
  __shared__ float xl[16][132];        // row stride >= 128 (D)!
  __shared__ __bf16 Qst[8][16][16];    // [head][l-row][col]
  __shared__ __bf16 Kst[8][16][16];    // [head][tau-permuted l-row][col]
  __shared__ __bf16 Vst[8][17][16];    // [head][dh-row 0-15, mask row 16][l-col]
  const int b = blockIdx.x >> 7;
  const int l0 = (blockIdx.x & 127) * 16;
  const int tid = threadIdx.x;

#pragma unroll
  for (int i = 0; i < 2; ++i) {
    int idx = i * 256 + tid;
    int d = idx >> 2;
    int l4 = (idx & 3) * 4;
    const float4 v = *(const float4*)&qin[(b * D_ + d) * L_ + l0 + l4];
    xl[l4 + 0][d] = v.x;
    xl[l4 + 1][d] = v.y;
    xl[l4 + 2][d] = v.z;
    xl[l4 + 3][d] = v.w;
  }

  // Mask row 16 of each head's Vst tile for our 16 columns.
  if (tid < 128) {
    const int hh = tid >> 4, c = tid & 15;
    Vst[hh][16][c] = (__bf16)(float)mask[b * L_ + l0 + c];
  }
  __syncthreads();

  const int lane = tid & 63, wave = tid >> 6;
  const int quad = lane >> 4, col = lane & 15;

  bf16x8 af[4];
#pragma unroll
  for (int kc = 0; kc < 4; ++kc) {
    const float* s = &xl[col][kc * 32 + quad * 8];
#pragma unroll
    for (int j = 0; j < 8; ++j) af[kc][j] = (__bf16)s[j];
  }

  const int quadK = ((quad & 1) << 1) | (quad >> 1);     // tau: swap bits 2,3
  const float mvv = (float)mask[b * L_ + l0 + col];      // V column mask

#pragma unroll
  for (int tt = 0; tt < 6; ++tt) {
    const int tile = wave * 6 + tt;
    floatx4 acc = {0.f, 0.f, 0.f, 0.f};
    const bool isV = (tile >= 16);
#pragma unroll
    for (int kc = 0; kc < 4; ++kc) {
      bf16x8 wf =
          *(const bf16x8*)(Wb + ((size_t)((tile * 4 + kc) * 64) + lane) * 8);
      acc = isV ? __builtin_amdgcn_mfma_f32_16x16x32_bf16(wf, af[kc], acc, 0, 0, 0)
                : __builtin_amdgcn_mfma_f32_16x16x32_bf16(af[kc], wf, acc, 0, 0, 0);
    }
    if (tile < 8) {  // Q head -> LDS
#pragma unroll
      for (int r = 0; r < 4; ++r) Qst[tile][quad * 4 + r][col] = (__bf16)acc[r];
    } else if (tile < 16) {  // K head, tau-permuted rows -> LDS
#pragma unroll
      for (int r = 0; r < 4; ++r)
        Kst[tile - 8][quadK * 4 + r][col] = (__bf16)acc[r];
    } else {  // V^T * mask -> LDS
#pragma unroll
      for (int r = 0; r < 4; ++r)
        Vst[tile - 16][quad * 4 + r][col] = (__bf16)(acc[r] * mvv);
    }
  }
  __syncthreads();

  // Cooperative coalesced stores.
  {
    const int hID = tid >> 5;           // 0..7
    const int u = tid & 31;             // 0..31
    const int row = u >> 1, ch = (u & 1) * 8;
    const size_t bhq = (size_t)(b * H_ + hID);
    bf16x8 qv = *(const bf16x8*)&Qst[hID][row][ch];
    *(bf16x8*)(Qs + (bhq * L_ + l0 + row) * DH_ + ch) = qv;
    bf16x8 kv = *(const bf16x8*)&Kst[hID][row][ch];
    *(bf16x8*)(Ks + (bhq * L_ + l0 + row) * DH_ + ch) = kv;
  }
  // V flat: 8 heads x 17 rows x 2 halves = 272 16B units into Vpx[bh][row][l].
#pragma unroll
  for (int pass = 0; pass < 2; ++pass) {
    const int u = pass * 256 + tid;
    if (u < 272) {
      const int hID = u / 34;
      const int w = u - hID * 34;
      const int row = w >> 1, ch = (w & 1) * 8;
      bf16x8 vv = *(const bf16x8*)&Vst[hID][row][ch];
      *(bf16x8*)(Vpx + ((size_t)(b * H_ + hID) * 32 + row) * L_ + l0 + ch) = vv;
    }
  }
}

// ---------------------------------------------------------------------------
// Key compaction v2 (round-6, unchanged): vectorized gather into flat
// Vpc[bh][row][l] and tau-permuted Ksc. Exact (masked keys contribute 0).
// grid = B*H * 25 blocks: slot 0-16 = V row, slot 17-24 = K segment.
// ---------------------------------------------------------------------------
__global__ __launch_bounds__(256) void compact_kernel(
    const int* __restrict__ sel, const int* __restrict__ cnt,
    const __bf16* __restrict__ Ks, const __bf16* __restrict__ Vpx,
    __bf16* __restrict__ Ksc, __bf16* __restrict__ Vpc) {
  const int bh = blockIdx.x / 25;
  const int slot = blockIdx.x % 25;
  const int b = bh >> 3;
  const int cn = cnt[b];
  const int pend = ((cn + 31) >> 5) << 5;  // zero-pad bound (32-aligned)
  const size_t bhb = (size_t)bh;
  const int tid = threadIdx.x;

  if (slot < 17) {  // V row gather: row `slot`, thread -> 8 consecutive p
    const int p0 = tid * 8;
    if (p0 >= pend) return;
    const __bf16* src = Vpx + (bhb * 32 + slot) * L_;
    const int* sp = sel + b * L_ + p0;
    bf16x8 v;
    if (p0 + 8 <= cn) {
      const int4 s0 = *(const int4*)sp;
      const int4 s1 = *(const int4*)(sp + 4);
      v[0] = src[s0.x]; v[1] = src[s0.y]; v[2] = src[s0.z]; v[3] = src[s0.w];
      v[4] = src[s1.x]; v[5] = src[s1.y]; v[6] = src[s1.z]; v[7] = src[s1.w];
    } else {
#pragma unroll
      for (int j = 0; j < 8; ++j)
        v[j] = (p0 + j < cn) ? src[sp[j]] : (__bf16)0.0f;
    }
    *(bf16x8*)(Vpc + (bhb * 32 + slot) * L_ + p0) = v;
  } else {  // K segment: thread -> one p
    const int p = (slot - 17) * 256 + tid;
    if (p >= pend) return;
    bf16x8* kdst = (bf16x8*)(Ksc + (bhb * L_ + tau16(p)) * DH_);
    if (p < cn) {
      const int l = sel[b * L_ + p];
      const bf16x8* ksrc = (const bf16x8*)(Ks + (bhb * L_ + tau16(l)) * DH_);
      kdst[0] = ksrc[0];
      kdst[1] = ksrc[1];
    } else {
      bf16x8 z = {};
      kdst[0] = z;
      kdst[1] = z;
    }
  }
}

// ---------------------------------------------------------------------------
// Attention (round-6, byte-identical): compacted keys, static 2-stage
// pipeline, dual-q, K-split wave pairs, XCD remap, flat V layout.
// v15 MEASUREMENT ROUND: this kernel is dispatched 4x (idempotent) so
// (total_v15 - total_v14)/3 = attn duration. Three consecutive
// misattributions mean the per-kernel time model must be re-anchored in a
// direct measurement before any further optimization.
// grid = B*H*(L/128) = 1024 blocks x 4 waves (wave: 64 q x ~16 kv-tiles).
// ---------------------------------------------------------------------------
__global__ __launch_bounds__(256, 4) void attn_kernel(
    const __bf16* __restrict__ Qs, const __bf16* __restrict__ Ks,
    const __bf16* __restrict__ Vp, const int* __restrict__ cnt,
    float* __restrict__ out) {
  __shared__ float red[2][64][33];  // 32 parked floats/lane, pad stride 33
  const int idx = blockIdx.x;
  const int qb = idx >> 6;        // 16 q-blocks of 128 rows
  const int bhi = idx & 63;       // bh minor -> idx%8 = h fixed per bh (XCD)
  const int h = bhi & 7;
  const int b = bhi >> 3;
  const int tid = threadIdx.x;
  const int lane = tid & 63, wave = tid >> 6;
  const int pair = wave >> 1;     // which 64 q-rows of this block
  const int half = wave & 1;      // which chunk of KV tiles
  const int n = lane & 31, hh = lane >> 5;
  const int q0 = qb * 128 + pair * 64;
  const size_t bh = (size_t)(b * H_ + h);

  // dynamic tile range: [tb, tb+ntw) of nt = ceil(cnt/32) compacted tiles
  const int cn = cnt[b];
  const int nt = (cn + 31) >> 5;
  const int nh0 = (nt + 1) >> 1;
  const int tb = half ? nh0 : 0;
  const int ntw = half ? (nt - nh0) : nh0;

  // Q B-frags: B[k=dh=8*hh+j][n=q] for q-rows q0+n and q0+32+n
  const bf16x8 qf0 = *(const bf16x8*)(Qs + (bh * L_ + q0 + n) * DH_ + 8 * hh);
  const bf16x8 qf1 =
      *(const bf16x8*)(Qs + (bh * L_ + q0 + 32 + n) * DH_ + 8 * hh);

  const __bf16* Kp = Ks + bh * L_ * DH_ + (size_t)n * DH_ + 8 * hh +
                     (size_t)tb * 32 * DH_;
  const __bf16* Vq = Vp + (bh * 32 + n) * (size_t)L_ + 8 * hh +
                     (size_t)tb * 32;

  floatx16 acc0, acc1;
#pragma unroll
  for (int r = 0; r < 16; ++r) { acc0[r] = 0.f; acc1[r] = 0.f; }
  const floatx16 zz = acc0;

  // one KV tile against both q-groups; all operands are named registers.
  auto compute = [&](const bf16x8& KF, const bf16x8& VA, const bf16x8& VB) {
    floatx16 s0 = __builtin_amdgcn_mfma_f32_32x32x16_bf16(KF, qf0, zz, 0, 0, 0);
    floatx16 s1 = __builtin_amdgcn_mfma_f32_32x32x16_bf16(KF, qf1, zz, 0, 0, 0);
    bf16x8 pA0, pB0, pA1, pB1;
#pragma unroll
    for (int j = 0; j < 8; ++j) pA0[j] = (__bf16)EXP2(s0[j]);
#pragma unroll
    for (int j = 0; j < 8; ++j) pB0[j] = (__bf16)EXP2(s0[8 + j]);
#pragma unroll
    for (int j = 0; j < 8; ++j) pA1[j] = (__bf16)EXP2(s1[j]);
#pragma unroll
    for (int j = 0; j < 8; ++j) pB1[j] = (__bf16)EXP2(s1[8 + j]);
    acc0 = __builtin_amdgcn_mfma_f32_32x32x16_bf16(VA, pA0, acc0, 0, 0, 0);
    acc0 = __builtin_amdgcn_mfma_f32_32x32x16_bf16(VB, pB0, acc0, 0, 0, 0);
    acc1 = __builtin_amdgcn_mfma_f32_32x32x16_bf16(VA, pA1, acc1, 0, 0, 0);
    acc1 = __builtin_amdgcn_mfma_f32_32x32x16_bf16(VB, pB1, acc1, 0, 0, 0);
  };

  // prologue: tile 0 of this wave's range into stage A
  bf16x8 kA = *(const bf16x8*)(Kp);
  bf16x8 vaA = *(const bf16x8*)(Vq);
  bf16x8 vbA = *(const bf16x8*)(Vq + 16);
  bf16x8 kB, vaB, vbB;

  int t = 0;
#pragma unroll 1
  for (; t + 2 <= ntw; t += 2) {
    // load tile t+1 into B (consumed after compute(A) -> latency hidden)
    kB  = *(const bf16x8*)(Kp + (size_t)(t + 1) * 32 * DH_);
    vaB = *(const bf16x8*)(Vq + (size_t)(t + 1) * 32);
    vbB = *(const bf16x8*)(Vq + (size_t)(t + 1) * 32 + 16);
    compute(kA, vaA, vbA);
    // load tile t+2 into A (guarded: redundant in-bounds reload at range end)
    const size_t t2 = (size_t)((t + 2 < ntw) ? t + 2 : t + 1);
    kA  = *(const bf16x8*)(Kp + t2 * 32 * DH_);
    vaA = *(const bf16x8*)(Vq + t2 * 32);
    vbA = *(const bf16x8*)(Vq + t2 * 32 + 16);
    compute(kB, vaB, vbB);
  }
  if (t < ntw) {  // odd tail: last tile already resident in A
    compute(kA, vaA, vbA);
  }

  // cross-wave K-reduction: half 0 parks both partial accs, half 1 sums.
  if (half == 0) {
#pragma unroll
    for (int r = 0; r < 16; ++r) {
      red[pair][lane][r] = acc0[r];
      red[pair][lane][16 + r] = acc1[r];
    }
  }
  __syncthreads();
  if (half == 0) return;
#pragma unroll
  for (int r = 0; r < 16; ++r) {
    acc0[r] += red[pair][lane][r];
    acc1[r] += red[pair][lane][16 + r];
  }

  // l = row 16 of O^T = acc reg 8 on the hh==0 half; broadcast to hh==1.
  float l0v = acc0[8];
  float l0o = __shfl_xor(l0v, 32, 64);
  float inv0 = __builtin_amdgcn_rcpf(hh ? l0o : l0v);
  float l1v = acc1[8];
  float l1o = __shfl_xor(l1v, 32, 64);
  float inv1 = __builtin_amdgcn_rcpf(hh ? l1o : l1v);

  // regs 0-7 are the 8 valid dh rows for this half: dh = (r&3)+8*(r>>2)+4*hh
  float* obase = out + ((size_t)(b * D_ + h * DH_)) * L_ + q0 + n;
#pragma unroll
  for (int r = 0; r < 8; ++r) {
    const int dh = (r & 3) + 8 * (r >> 2) + 4 * hh;
    obase[(size_t)dh * L_] = acc0[r] * inv0;
    obase[(size_t)dh * L_ + 32] = acc1[r] * inv1;
  }
}

// ---------------------------------------------------------------------------
extern "C" void kernel_launch(void* const* d_in, const int* in_sizes, int n_in,
                              void* d_out, int out_size, void* d_ws,
                              size_t ws_size, hipStream_t stream) {
  const float* queries = (const float*)d_in[0];  // [B, D, L] fp32
  const int*   mask    = (const int*)d_in[1];    // [B, L] int32
  const float* wmem    = (const float*)d_in[2];  // [2D, D] fp32
  const float* wq      = (const float*)d_in[3];  // [D, D] fp32
  float* out = (float*)d_out;                    // [B, D, L] fp32

  // Workspace layout (SEG = 4 MiB):
  //   0: Qs | 1: Ks dense | 2-3: Vpx flat dense | 4: Ksc | 5-6: Vpc flat |
  //   7: sel [B][L] int (64KB) + cnt [B] int
  const size_t SEG = (size_t)B_ * H_ * L_ * DH_ * sizeof(__bf16);
  __bf16* Qs  = (__bf16*)d_ws;
  __bf16* Ks  = (__bf16*)((char*)d_ws + SEG);
  __bf16* Vpx = (__bf16*)((char*)d_ws + 2 * SEG);
  __bf16* Ksc = (__bf16*)((char*)d_ws + 4 * SEG);
  __bf16* Vpc = (__bf16*)((char*)d_ws + 5 * SEG);
  int* sel = (int*)((char*)d_ws + 7 * SEG);
  int* cnt = sel + B_ * L_;

  // Wb (96 KiB) in d_out scratch: wconv writes, proj reads, attn then
  // overwrites ALL of d_out — stream-ordered, race-free.
  __bf16* Wb = (__bf16*)((char*)d_out + (4u << 20));

  scan_kernel<<<B_, 256, 0, stream>>>(mask, sel, cnt);
  wconv_kernel<<<24, 256, 0, stream>>>(wmem, wq, Wb);
  proj_kernel<<<B_ * (L_ / 16), 256, 0, stream>>>(queries, mask, Wb, Qs, Ks, Vpx);
  compact_kernel<<<B_ * H_ * 25, 256, 0, stream>>>(sel, cnt, Ks, Vpx, Ksc, Vpc);
  // MEASUREMENT: attn dispatched 4x (idempotent). (total-118)/3 = attn dur.
  attn_kernel<<<B_ * H_ * (L_ / 128), 256, 0, stream>>>(Qs, Ksc, Vpc, cnt, out);
  attn_kernel<<<B_ * H_ * (L_ / 128), 256, 0, stream>>>(Qs, Ksc, Vpc, cnt, out);
  attn_kernel<<<B_ * H_ * (L_ / 128), 256, 0, stream>>>(Qs, Ksc, Vpc, cnt, out);
  attn_kernel<<<B_ * H_ * (L_ / 128), 256, 0, stream>>>(Qs, Ksc, Vpc, cnt, out);
}

// Round 8
// 113.098 us; speedup vs baseline: 1.5828x; 1.5828x over previous
//
#include <hip/hip_runtime.h>
#include <math.h>

// Problem constants
#define B_  8
#define D_  128
#define L_  2048
#define H_  8
#define DH_ 16

#define LOG2E 1.4426950408889634f

typedef __bf16 bf16x8 __attribute__((ext_vector_type(8)));
typedef float  floatx4 __attribute__((ext_vector_type(4)));
typedef float  floatx16 __attribute__((ext_vector_type(16)));

#if __has_builtin(__builtin_amdgcn_exp2f)
#define EXP2(x) __builtin_amdgcn_exp2f(x)
#else
#define EXP2(x) exp2f(x)
#endif

// tau: swap bits 2,3 of a row index (K A-frag row permutation, involution
// within each aligned 16-row group; bijection on [0,L)).
__device__ __forceinline__ int tau16(int x) {
  return (x & ~12) | ((x & 4) << 1) | ((x & 8) >> 1);
}

// ---------------------------------------------------------------------------
// Weight pre-convert: fp32 W -> bf16 MFMA frag layout (lane idx = col,
// k = quad*8+j). tiles 0..7 = Q heads (W_q pre-scaled by DH^-0.5 * log2e so
// attn softmax is exp2(s)), 8..15 = K, 16..23 = V.
// ---------------------------------------------------------------------------
__global__ __launch_bounds__(256) void wconv_kernel(
    const float* __restrict__ wmem, const float* __restrict__ wq,
    __bf16* __restrict__ Wb) {
  const int tile = blockIdx.x;
  const int tid = threadIdx.x;
  const int kc = tid >> 6, lane = tid & 63;
  const int quad = lane >> 4, col = lane & 15;
  const float* src;
  float scale = 1.0f;
  if (tile < 8) {
    src = wq + (tile * 16 + col) * D_;
    scale = 0.25f * LOG2E;  // DH^-0.5 and log2e folded into W_q
  } else if (tile < 16) {
    src = wmem + ((tile - 8) * 16 + col) * D_;
  } else {
    src = wmem + (128 + (tile - 16) * 16 + col) * D_;
  }
  const float* p = src + kc * 32 + quad * 8;
  bf16x8 w;
#pragma unroll
  for (int j = 0; j < 8; ++j) w[j] = (__bf16)(p[j] * scale);
  *(bf16x8*)(Wb + ((size_t)((tile * 4 + kc) * 64) + lane) * 8) = w;
}

// ---------------------------------------------------------------------------
// Mask prefix scan v2: per batch b, pos[b][l] = compacted index of key l
// (valid only where mask=1), cnt[b] = number of unmasked keys. ALSO
// zero-fills the pad region [cnt, pend) of Ksc (rows tau16(p), 32B each)
// and Vpc (columns p, rows 0..16) for all 8 heads, so proj only has to
// write the valid entries. Pad contributes exactly 0 to the attention sums
// (K=0 -> exp2(0)=1 x V=0; mask row 0). One block per b.
// ---------------------------------------------------------------------------
__global__ __launch_bounds__(256) void scan_kernel(
    const int* __restrict__ mask, int* __restrict__ pos,
    int* __restrict__ cnt, __bf16* __restrict__ Ksc,
    __bf16* __restrict__ Vpc) {
  __shared__ int tsum[256];
  __shared__ int tbase[256];
  __shared__ int cns;
  const int b = blockIdx.x, tid = threadIdx.x;
  int m[8], s = 0;
  const int* mp = mask + b * L_ + tid * 8;
#pragma unroll
  for (int j = 0; j < 8; ++j) { m[j] = mp[j]; s += m[j]; }
  tsum[tid] = s;
  __syncthreads();
  if (tid == 0) {
    int a = 0;
#pragma unroll 1
    for (int i = 0; i < 256; ++i) { tbase[i] = a; a += tsum[i]; }
    cnt[b] = a;
    cns = a;
  }
  __syncthreads();
  int p = tbase[tid];
  int* pb = pos + b * L_;
#pragma unroll
  for (int j = 0; j < 8; ++j) {
    if (m[j]) pb[tid * 8 + j] = p++;
  }
  // zero-pad: thread -> (head, dp); p = cn + dp < pend.
  const int cn = cns;
  const int pend = ((cn + 31) >> 5) << 5;
  const int hID = tid >> 5, dp = tid & 31;
  const int pp = cn + dp;
  if (pp < pend) {
    const size_t bh = (size_t)(b * H_ + hID);
    bf16x8 z = {};
    bf16x8* kd = (bf16x8*)(Ksc + (bh * L_ + tau16(pp)) * DH_);
    kd[0] = z;
    kd[1] = z;
    __bf16* vd = Vpc + (bh * 32) * (size_t)L_ + pp;
#pragma unroll
    for (int r = 0; r <= 16; ++r) vd[(size_t)r * L_] = (__bf16)0.0f;
  }
}

// ---------------------------------------------------------------------------
// Projection v4: compaction FOLDED IN (compact kernel deleted).
//   Post-mortem v15 measurement: attn = 20.3us; scan+compact ~ 25us -- the
//   separate compact pass (1M+ scalar gather transactions + re-reading the
//   12MB proj just wrote) cost more than attn's savings. proj holds every
//   K/V value at store time, so with pos[] it writes compacted directly:
//   K: LDS-staged at natural rows; store pass writes only masked rows as
//      2x16B vectors to Ksc[tau16(pos[l])] (scattered, vector).
//   V: store pass writes only masked columns; consecutive masked l ->
//      consecutive p -> the per-row scalar stores coalesce. Mask row = 1.0.
//   Q: unchanged.
// ---------------------------------------------------------------------------
__global__ __launch_bounds__(256) void proj_kernel(
    const float* __restrict__ qin, const int* __restrict__ mask,
    const int* __restrict__ pos, const __bf16* __restrict__ Wb,
    __bf16* __restrict__ Qs, __bf16* __restrict__ Ksc,
    __bf16* __restrict__ Vpc) {
  __shared__ float xl[16][132];        // row stride >= 128 (D)!
  __shared__ __bf16 Qst[8][16][16];    // [head][l-row][col]
  __shared__ __bf16 Kst[8][16][16];    // [head][natural l-row][dh-col]
  __shared__ __bf16 Vst[8][16][16];    // [head][dh-row][l-col]
  const int b = blockIdx.x >> 7;
  const int l0 = (blockIdx.x & 127) * 16;
  const int tid = threadIdx.x;

#pragma unroll
  for (int i = 0; i < 2; ++i) {
    int idx = i * 256 + tid;
    int d = idx >> 2;
    int l4 = (idx & 3) * 4;
    const float4 v = *(const float4*)&qin[(b * D_ + d) * L_ + l0 + l4];
    xl[l4 + 0][d] = v.x;
    xl[l4 + 1][d] = v.y;
    xl[l4 + 2][d] = v.z;
    xl[l4 + 3][d] = v.w;
  }
  __syncthreads();

  const int lane = tid & 63, wave = tid >> 6;
  const int quad = lane >> 4, col = lane & 15;

  bf16x8 af[4];
#pragma unroll
  for (int kc = 0; kc < 4; ++kc) {
    const float* s = &xl[col][kc * 32 + quad * 8];
#pragma unroll
    for (int j = 0; j < 8; ++j) af[kc][j] = (__bf16)s[j];
  }

#pragma unroll
  for (int tt = 0; tt < 6; ++tt) {
    const int tile = wave * 6 + tt;
    floatx4 acc = {0.f, 0.f, 0.f, 0.f};
    const bool isV = (tile >= 16);
#pragma unroll
    for (int kc = 0; kc < 4; ++kc) {
      bf16x8 wf =
          *(const bf16x8*)(Wb + ((size_t)((tile * 4 + kc) * 64) + lane) * 8);
      acc = isV ? __builtin_amdgcn_mfma_f32_16x16x32_bf16(wf, af[kc], acc, 0, 0, 0)
                : __builtin_amdgcn_mfma_f32_16x16x32_bf16(af[kc], wf, acc, 0, 0, 0);
    }
    if (tile < 8) {  // Q head -> LDS
#pragma unroll
      for (int r = 0; r < 4; ++r) Qst[tile][quad * 4 + r][col] = (__bf16)acc[r];
    } else if (tile < 16) {  // K head -> LDS, natural rows
#pragma unroll
      for (int r = 0; r < 4; ++r)
        Kst[tile - 8][quad * 4 + r][col] = (__bf16)acc[r];
    } else {  // V^T -> LDS
#pragma unroll
      for (int r = 0; r < 4; ++r)
        Vst[tile - 16][quad * 4 + r][col] = (__bf16)acc[r];
    }
  }
  __syncthreads();

  // Q: coalesced 16B stores (unchanged).  K: compacted scattered 16B stores.
  {
    const int hID = tid >> 5;           // 0..7
    const int u = tid & 31;             // 0..31
    const int row = u >> 1, ch = (u & 1) * 8;
    const size_t bhq = (size_t)(b * H_ + hID);
    bf16x8 qv = *(const bf16x8*)&Qst[hID][row][ch];
    *(bf16x8*)(Qs + (bhq * L_ + l0 + row) * DH_ + ch) = qv;
    const int lK = l0 + row;
    if (mask[b * L_ + lK]) {
      const int p = pos[b * L_ + lK];
      bf16x8 kv = *(const bf16x8*)&Kst[hID][row][ch];
      *(bf16x8*)(Ksc + (bhq * L_ + tau16(p)) * DH_ + ch) = kv;
    }
  }
  // V: compacted column stores. thread -> (head, l-col); consecutive masked
  // cols -> consecutive p -> coalesced per dh-row. Mask row 16 = 1.0.
  if (tid < 128) {
    const int hV = tid >> 4, c = tid & 15;
    const int lV = l0 + c;
    if (mask[b * L_ + lV]) {
      const int p = pos[b * L_ + lV];
      __bf16* dst = Vpc + ((size_t)(b * H_ + hV) * 32) * L_ + p;
#pragma unroll
      for (int r = 0; r < 16; ++r) dst[(size_t)r * L_] = Vst[hV][r][c];
      dst[(size_t)16 * L_] = (__bf16)1.0f;
    }
  }
}

// ---------------------------------------------------------------------------
// Attention (round-6 structure, byte-identical math): compacted keys,
// static 2-stage pipeline, dual-q, K-split wave pairs, XCD remap, flat V.
// Directly measured (v15 4x-dispatch): 20.3 us.
// grid = B*H*(L/128) = 1024 blocks x 4 waves (wave: 64 q x ~16 kv-tiles).
// ---------------------------------------------------------------------------
__global__ __launch_bounds__(256, 4) void attn_kernel(
    const __bf16* __restrict__ Qs, const __bf16* __restrict__ Ks,
    const __bf16* __restrict__ Vp, const int* __restrict__ cnt,
    float* __restrict__ out) {
  __shared__ float red[2][64][33];  // 32 parked floats/lane, pad stride 33
  const int idx = blockIdx.x;
  const int qb = idx >> 6;        // 16 q-blocks of 128 rows
  const int bhi = idx & 63;       // bh minor -> idx%8 = h fixed per bh (XCD)
  const int h = bhi & 7;
  const int b = bhi >> 3;
  const int tid = threadIdx.x;
  const int lane = tid & 63, wave = tid >> 6;
  const int pair = wave >> 1;     // which 64 q-rows of this block
  const int half = wave & 1;      // which chunk of KV tiles
  const int n = lane & 31, hh = lane >> 5;
  const int q0 = qb * 128 + pair * 64;
  const size_t bh = (size_t)(b * H_ + h);

  // dynamic tile range: [tb, tb+ntw) of nt = ceil(cnt/32) compacted tiles
  const int cn = cnt[b];
  const int nt = (cn + 31) >> 5;
  const int nh0 = (nt + 1) >> 1;
  const int tb = half ? nh0 : 0;
  const int ntw = half ? (nt - nh0) : nh0;

  // Q B-frags: B[k=dh=8*hh+j][n=q] for q-rows q0+n and q0+32+n
  const bf16x8 qf0 = *(const bf16x8*)(Qs + (bh * L_ + q0 + n) * DH_ + 8 * hh);
  const bf16x8 qf1 =
      *(const bf16x8*)(Qs + (bh * L_ + q0 + 32 + n) * DH_ + 8 * hh);

  const __bf16* Kp = Ks + bh * L_ * DH_ + (size_t)n * DH_ + 8 * hh +
                     (size_t)tb * 32 * DH_;
  const __bf16* Vq = Vp + (bh * 32 + n) * (size_t)L_ + 8 * hh +
                     (size_t)tb * 32;

  floatx16 acc0, acc1;
#pragma unroll
  for (int r = 0; r < 16; ++r) { acc0[r] = 0.f; acc1[r] = 0.f; }
  const floatx16 zz = acc0;

  // one KV tile against both q-groups; all operands are named registers.
  auto compute = [&](const bf16x8& KF, const bf16x8& VA, const bf16x8& VB) {
    floatx16 s0 = __builtin_amdgcn_mfma_f32_32x32x16_bf16(KF, qf0, zz, 0, 0, 0);
    floatx16 s1 = __builtin_amdgcn_mfma_f32_32x32x16_bf16(KF, qf1, zz, 0, 0, 0);
    bf16x8 pA0, pB0, pA1, pB1;
#pragma unroll
    for (int j = 0; j < 8; ++j) pA0[j] = (__bf16)EXP2(s0[j]);
#pragma unroll
    for (int j = 0; j < 8; ++j) pB0[j] = (__bf16)EXP2(s0[8 + j]);
#pragma unroll
    for (int j = 0; j < 8; ++j) pA1[j] = (__bf16)EXP2(s1[j]);
#pragma unroll
    for (int j = 0; j < 8; ++j) pB1[j] = (__bf16)EXP2(s1[8 + j]);
    acc0 = __builtin_amdgcn_mfma_f32_32x32x16_bf16(VA, pA0, acc0, 0, 0, 0);
    acc0 = __builtin_amdgcn_mfma_f32_32x32x16_bf16(VB, pB0, acc0, 0, 0, 0);
    acc1 = __builtin_amdgcn_mfma_f32_32x32x16_bf16(VA, pA1, acc1, 0, 0, 0);
    acc1 = __builtin_amdgcn_mfma_f32_32x32x16_bf16(VB, pB1, acc1, 0, 0, 0);
  };

  // prologue: tile 0 of this wave's range into stage A
  bf16x8 kA = *(const bf16x8*)(Kp);
  bf16x8 vaA = *(const bf16x8*)(Vq);
  bf16x8 vbA = *(const bf16x8*)(Vq + 16);
  bf16x8 kB, vaB, vbB;

  int t = 0;
#pragma unroll 1
  for (; t + 2 <= ntw; t += 2) {
    // load tile t+1 into B (consumed after compute(A) -> latency hidden)
    kB  = *(const bf16x8*)(Kp + (size_t)(t + 1) * 32 * DH_);
    vaB = *(const bf16x8*)(Vq + (size_t)(t + 1) * 32);
    vbB = *(const bf16x8*)(Vq + (size_t)(t + 1) * 32 + 16);
    compute(kA, vaA, vbA);
    // load tile t+2 into A (guarded: redundant in-bounds reload at range end)
    const size_t t2 = (size_t)((t + 2 < ntw) ? t + 2 : t + 1);
    kA  = *(const bf16x8*)(Kp + t2 * 32 * DH_);
    vaA = *(const bf16x8*)(Vq + t2 * 32);
    vbA = *(const bf16x8*)(Vq + t2 * 32 + 16);
    compute(kB, vaB, vbB);
  }
  if (t < ntw) {  // odd tail: last tile already resident in A
    compute(kA, vaA, vbA);
  }

  // cross-wave K-reduction: half 0 parks both partial accs, half 1 sums.
  if (half == 0) {
#pragma unroll
    for (int r = 0; r < 16; ++r) {
      red[pair][lane][r] = acc0[r];
      red[pair][lane][16 + r] = acc1[r];
    }
  }
  __syncthreads();
  if (half == 0) return;
#pragma unroll
  for (int r = 0; r < 16; ++r) {
    acc0[r] += red[pair][lane][r];
    acc1[r] += red[pair][lane][16 + r];
  }

  // l = row 16 of O^T = acc reg 8 on the hh==0 half; broadcast to hh==1.
  float l0v = acc0[8];
  float l0o = __shfl_xor(l0v, 32, 64);
  float inv0 = __builtin_amdgcn_rcpf(hh ? l0o : l0v);
  float l1v = acc1[8];
  float l1o = __shfl_xor(l1v, 32, 64);
  float inv1 = __builtin_amdgcn_rcpf(hh ? l1o : l1v);

  // regs 0-7 are the 8 valid dh rows for this half: dh = (r&3)+8*(r>>2)+4*hh
  float* obase = out + ((size_t)(b * D_ + h * DH_)) * L_ + q0 + n;
#pragma unroll
  for (int r = 0; r < 8; ++r) {
    const int dh = (r & 3) + 8 * (r >> 2) + 4 * hh;
    obase[(size_t)dh * L_] = acc0[r] * inv0;
    obase[(size_t)dh * L_ + 32] = acc1[r] * inv1;
  }
}

// ---------------------------------------------------------------------------
extern "C" void kernel_launch(void* const* d_in, const int* in_sizes, int n_in,
                              void* d_out, int out_size, void* d_ws,
                              size_t ws_size, hipStream_t stream) {
  const float* queries = (const float*)d_in[0];  // [B, D, L] fp32
  const int*   mask    = (const int*)d_in[1];    // [B, L] int32
  const float* wmem    = (const float*)d_in[2];  // [2D, D] fp32
  const float* wq      = (const float*)d_in[3];  // [D, D] fp32
  float* out = (float*)d_out;                    // [B, D, L] fp32

  // Workspace layout (SEG = 4 MiB):
  //   0: Qs | 1: Ksc (compacted, tau rows) | 2-3: Vpc flat [bh][32][L] |
  //   4: pos [B][L] int (64KB) + cnt [B] int
  const size_t SEG = (size_t)B_ * H_ * L_ * DH_ * sizeof(__bf16);
  __bf16* Qs  = (__bf16*)d_ws;
  __bf16* Ksc = (__bf16*)((char*)d_ws + SEG);
  __bf16* Vpc = (__bf16*)((char*)d_ws + 2 * SEG);
  int* pos = (int*)((char*)d_ws + 4 * SEG);
  int* cnt = pos + B_ * L_;

  // Wb (96 KiB) in d_out scratch: wconv writes, proj reads, attn then
  // overwrites ALL of d_out — stream-ordered, race-free.
  __bf16* Wb = (__bf16*)((char*)d_out + (4u << 20));

  scan_kernel<<<B_, 256, 0, stream>>>(mask, pos, cnt, Ksc, Vpc);
  wconv_kernel<<<24, 256, 0, stream>>>(wmem, wq, Wb);
  proj_kernel<<<B_ * (L_ / 16), 256, 0, stream>>>(queries, mask, pos, Wb, Qs,
                                                  Ksc, Vpc);
  attn_kernel<<<B_ * H_ * (L_ / 128), 256, 0, stream>>>(Qs, Ksc, Vpc, cnt, out);
}